// Round 3
// baseline (359.602 us; speedup 1.0000x reference)
//
#include <hip/hip_runtime.h>

#define O_DIM   1024
#define C_DIM   512
#define HW      784
#define B_DIM   32
#define T_POS   8                // 8 consecutive n per wg => 32B-sector-clean HBM
#define NTILES  (HW / T_POS)     // 98
#define NTHREADS 256

typedef float v2f __attribute__((ext_vector_type(2)));

// complex multiply via packed fp32: (a.x*b.x - a.y*b.y, a.x*b.y + a.y*b.x)
// compiles to v_pk_mul_f32 + v_pk_fma_f32 (neg folded into modifiers)
__device__ __forceinline__ v2f cmul(v2f a, v2f b) {
    v2f bs = __builtin_shufflevector(b, b, 1, 0);   // (b.y, b.x)
    v2f an = {-a.y, a.y};
    return a.x * b + an * bs;
}

static constexpr int REV5[32] = {
    0,16,8,24,4,20,12,28,2,18,10,26,6,22,14,30,
    1,17,9,25,5,21,13,29,3,19,11,27,7,23,15,31};

static constexpr float C32T[16] = {
    1.f, 0.98078528f, 0.92387953f, 0.83146961f,
    0.70710678f, 0.55557023f, 0.38268343f, 0.19509032f,
    0.f, -0.19509032f, -0.38268343f, -0.55557023f,
    -0.70710678f, -0.83146961f, -0.92387953f, -0.98078528f};
static constexpr float S32T[16] = {
    0.f, 0.19509032f, 0.38268343f, 0.55557023f,
    0.70710678f, 0.83146961f, 0.92387953f, 0.98078528f,
    1.f, 0.98078528f, 0.92387953f, 0.83146961f,
    0.70710678f, 0.55557023f, 0.38268343f, 0.19509032f};

// 32-point in-register DIF FFT, FORWARD only (inverse goes through the
// conjugation identity). Input natural order; output y[i] = X[rev5(i)].
__device__ __forceinline__ void fft32f(v2f y[32]) {
#pragma unroll
    for (int s = 0; s < 5; ++s) {
        const int L = 32 >> s;
        const int h = 16 >> s;
#pragma unroll
        for (int u = 0; u < 16; ++u) {
            const int blk = u >> (4 - s);
            const int t   = u & (h - 1);
            const int i   = blk * L + t;
            const int m   = t << s;            // twiddle index: W32^m
            v2f a = y[i], b = y[i + h];
            y[i] = a + b;
            v2f d = a - b;
            if (m == 0) {
                y[i + h] = d;
            } else if (m == 8) {
                y[i + h] = (v2f){d.y, -d.x};   // * -i  (forward)
            } else {
                y[i + h] = cmul(d, (v2f){C32T[m], -S32T[m]});
            }
        }
    }
}

// Second half of the four-step (forward sign): y[rev5(k2)] = A[p][k2] on entry.
// Twiddle by W1024^(-p*k2) (4 independent chains, depth ~12), scatter to
// swizzled rows, same-wave transpose read, final fft32.
// On return y[rev5(k1)] = X[p + 32*k1].
__device__ __forceinline__ void four_step_Bf(v2f* zg, int p, v2f y[32]) {
    float sv, cv;
    __sincosf(-6.283185307179586f * (float)p * (1.f / 1024.f), &sv, &cv);
    const v2f stw = {cv, sv};                    // W1024^(-p)
    v2f t2  = cmul(stw, stw);
    v2f t4  = cmul(t2, t2);
    v2f s8  = cmul(t4, t4);                      // stw^8
    v2f s16 = cmul(s8, s8);                      // stw^16
    v2f s24 = cmul(s16, s8);                     // stw^24
    v2f wq0 = {1.f, 0.f}, wq1 = s8, wq2 = s16, wq3 = s24;
#pragma unroll
    for (int m = 0; m < 8; ++m) {
        {   const int k2 = m;                     // chain 0
            v2f val = y[REV5[k2]];
            if (k2 > 0) val = cmul(val, wq0);
            zg[k2 * 32 + ((p + k2) & 31)] = val; }
        {   const int k2 = 8 + m;                 // chain 1
            zg[k2 * 32 + ((p + k2) & 31)] = cmul(y[REV5[k2]], wq1); }
        {   const int k2 = 16 + m;                // chain 2
            zg[k2 * 32 + ((p + k2) & 31)] = cmul(y[REV5[k2]], wq2); }
        {   const int k2 = 24 + m;                // chain 3
            zg[k2 * 32 + ((p + k2) & 31)] = cmul(y[REV5[k2]], wq3); }
        if (m < 7) {
            wq0 = cmul(wq0, stw); wq1 = cmul(wq1, stw);
            wq2 = cmul(wq2, stw); wq3 = cmul(wq3, stw);
        }
    }
    __builtin_amdgcn_wave_barrier();
#pragma unroll
    for (int n1 = 0; n1 < 32; ++n1)
        y[n1] = zg[p * 32 + ((n1 + p) & 31)];
    __builtin_amdgcn_wave_barrier();
    fft32f(y);
}

// One block per output row o; lanes sweep c coalesced. Each column c has
// exactly one nonzero across o, so the winning thread writes without races.
__global__ void extract_sketch(const float* __restrict__ sk1,
                               const float* __restrict__ sk2,
                               int* __restrict__ h, float* __restrict__ s) {
    const int o = blockIdx.x;                 // 0..1023
    for (int c = threadIdx.x; c < C_DIM; c += blockDim.x) {
        float v1 = sk1[o * C_DIM + c];
        if (v1 != 0.f) { h[c] = o; s[c] = v1; }
        float v2 = sk2[o * C_DIM + c];
        if (v2 != 0.f) { h[C_DIM + c] = o; s[C_DIM + c] = v2; }
    }
}

__global__ __launch_bounds__(NTHREADS, 2)
void cbp_main(const float* __restrict__ x1, const float* __restrict__ x2,
              const int* __restrict__ h1, const int* __restrict__ h2,
              const float* __restrict__ s1, const float* __restrict__ s2,
              float* __restrict__ out) {
    // 64 KB: Z = [8][1024] complex for scatter+FFT; after the FFTs die,
    // the same space is reused as R = [1024][10] floats (pad 10 -> 2-way
    // bank aliasing only, 8B-aligned rows) for the output transpose.
    __shared__ float4 LBUF[4096];
    float* Zs = reinterpret_cast<float*>(LBUF);    // scalar view (atomics)
    float* R  = reinterpret_cast<float*>(LBUF);    // transpose overlay

    const int tid  = threadIdx.x;
    const int b    = blockIdx.x / NTILES;
    const int tile = blockIdx.x % NTILES;
    const int n0   = tile * T_POS;

    // ---- prefetch x-tile (two channel rows per thread, 32 B each) ----
    const int c0 = tid;
    const int c1 = tid + NTHREADS;
    const int xoff = b * (C_DIM * HW) + n0;
    const float4* p10 = (const float4*)(x1 + xoff + c0 * HW);
    const float4* p11 = (const float4*)(x1 + xoff + c1 * HW);
    const float4* p20 = (const float4*)(x2 + xoff + c0 * HW);
    const float4* p21 = (const float4*)(x2 + xoff + c1 * HW);
    float4 a0 = p10[0], a1 = p10[1];   // x1 row c0, n0..n0+7
    float4 b0 = p11[0], b1 = p11[1];   // x1 row c1
    float4 d0 = p20[0], d1 = p20[1];   // x2 row c0
    float4 e0 = p21[0], e1 = p21[1];   // x2 row c1
    const int   q10 = h1[c0], q11 = h1[c1], q20 = h2[c0], q21 = h2[c1];
    const float w10 = s1[c0], w11 = s1[c1], w20 = s2[c0], w21 = s2[c1];

    // ---- zero LDS (hides the global-load latency) ----
#pragma unroll
    for (int i = 0; i < 4096 / NTHREADS; ++i)
        LBUF[tid + NTHREADS * i] = make_float4(0.f, 0.f, 0.f, 0.f);
    __syncthreads();

    // ---- scatter: Z[pos][h1[c]].x += s1*x1, Z[pos][h2[c]].y += s2*x2 ----
    {
        float v[8];
        v[0]=a0.x; v[1]=a0.y; v[2]=a0.z; v[3]=a0.w;
        v[4]=a1.x; v[5]=a1.y; v[6]=a1.z; v[7]=a1.w;
#pragma unroll
        for (int j = 0; j < 8; ++j)
            atomicAdd(&Zs[(j * O_DIM + q10) * 2 + 0], w10 * v[j]);
        v[0]=b0.x; v[1]=b0.y; v[2]=b0.z; v[3]=b0.w;
        v[4]=b1.x; v[5]=b1.y; v[6]=b1.z; v[7]=b1.w;
#pragma unroll
        for (int j = 0; j < 8; ++j)
            atomicAdd(&Zs[(j * O_DIM + q11) * 2 + 0], w11 * v[j]);
        v[0]=d0.x; v[1]=d0.y; v[2]=d0.z; v[3]=d0.w;
        v[4]=d1.x; v[5]=d1.y; v[6]=d1.z; v[7]=d1.w;
#pragma unroll
        for (int j = 0; j < 8; ++j)
            atomicAdd(&Zs[(j * O_DIM + q20) * 2 + 1], w20 * v[j]);
        v[0]=e0.x; v[1]=e0.y; v[2]=e0.z; v[3]=e0.w;
        v[4]=e1.x; v[5]=e1.y; v[6]=e1.z; v[7]=e1.w;
#pragma unroll
        for (int j = 0; j < 8; ++j)
            atomicAdd(&Zs[(j * O_DIM + q21) * 2 + 1], w21 * v[j]);
    }
    __syncthreads();

    const int g    = tid >> 5;       // position group 0..7 (half-wave)
    const int p    = tid & 31;
    const int lane = tid & 63;
    v2f* zg = reinterpret_cast<v2f*>(LBUF) + g * O_DIM;
    const int paddr = (((lane & 32) | ((32 - p) & 31))) << 2;

    v2f y[32];

    // Two iterations of the SAME forward-FFT code path (code emitted once):
    //   iter 0: forward FFT of z = p1 + i*p2 from LDS
    //   iter 1: inverse FFT of the Hermitian product, via the conjugation
    //           identity IFFT(G) = conj(FFT(conj(G))). conj(G) is folded
    //           into the product signs (free); the final conj is free too,
    //           because only the real part is stored.
#pragma unroll 1
    for (int iter = 0; iter < 2; ++iter) {
        if (iter == 0) {
#pragma unroll
            for (int n2 = 0; n2 < 32; ++n2)
                y[n2] = zg[p + 32 * n2];
            __builtin_amdgcn_wave_barrier();
        } else {
            // ---- Hermitian unpack + pointwise product, in registers ----
            // G[k], k = p+32*n2, needs zb = X[1024-k] which lives at lane
            // (32-p)&31, reg REV5[31-n2] (p>=1): fixed pairing -> bpermute.
            // Lane 0 self-patches from reg REV5[(32-n2)&31].
            // Scales (2x 0.5) folded into the final store (1/4096).
            v2f t[32];
#pragma unroll
            for (int n2 = 0; n2 < 32; ++n2) {
                v2f za = y[REV5[n2]];
                v2f yb = y[REV5[31 - n2]];
                v2f zb;
                zb.x = __uint_as_float((unsigned)__builtin_amdgcn_ds_bpermute(
                           paddr, (int)__float_as_uint(yb.x)));
                zb.y = __uint_as_float((unsigned)__builtin_amdgcn_ds_bpermute(
                           paddr, (int)__float_as_uint(yb.y)));
                v2f self = y[REV5[(32 - n2) & 31]];
                zb.x = (p == 0) ? self.x : zb.x;
                zb.y = (p == 0) ? self.y : zb.y;
                v2f F1c = { za.x + zb.x, zb.y - za.y };   // conj(2*F1)
                v2f F2c = { za.y + zb.y, za.x - zb.x };   // conj(2*F2)
                t[n2] = cmul(F1c, F2c);                   // conj(4*G[p+32n2])
            }
#pragma unroll
            for (int i = 0; i < 32; ++i) y[i] = t[i];
        }
        fft32f(y);
        four_step_Bf(zg, p, y);
    }
    __syncthreads();              // all groups done with Z before R overlay

    // ---- stage transpose: R[o][g] = conv[pos g][bucket o] ----
#pragma unroll
    for (int k1 = 0; k1 < 32; ++k1)
        R[(p + 32 * k1) * 10 + g] = y[REV5[k1]].x * (0.25f / 1024.f);
    __syncthreads();

    // ---- store: 32 B (8 consecutive n) per o, sector-clean ----
    const int obase = b * (O_DIM * HW) + n0;
#pragma unroll
    for (int r = 0; r < O_DIM / NTHREADS; ++r) {
        const int o = tid + NTHREADS * r;
        const float* rp = &R[o * 10];
        float4 v0 = make_float4(rp[0], rp[1], rp[2], rp[3]);
        float4 v1 = make_float4(rp[4], rp[5], rp[6], rp[7]);
        float4* dst = (float4*)(out + obase + o * HW);
        dst[0] = v0;
        dst[1] = v1;
    }
}

extern "C" void kernel_launch(void* const* d_in, const int* in_sizes, int n_in,
                              void* d_out, int out_size, void* d_ws, size_t ws_size,
                              hipStream_t stream) {
    const float* x1  = (const float*)d_in[0];
    const float* x2  = (const float*)d_in[1];
    const float* sk1 = (const float*)d_in[2];
    const float* sk2 = (const float*)d_in[3];
    float* out = (float*)d_out;

    int*   h = (int*)d_ws;                         // [0..511]=h1, [512..1023]=h2
    float* s = (float*)((char*)d_ws + 4096);       // [0..511]=s1, [512..1023]=s2

    hipLaunchKernelGGL(extract_sketch, dim3(O_DIM), dim3(256), 0, stream,
                       sk1, sk2, h, s);
    hipLaunchKernelGGL(cbp_main, dim3(B_DIM * NTILES), dim3(NTHREADS), 0, stream,
                       x1, x2, h, h + C_DIM, s, s + C_DIM, out);
}

// Round 4
// 353.638 us; speedup vs baseline: 1.0169x; 1.0169x over previous
//
#include <hip/hip_runtime.h>

#define O_DIM   1024
#define C_DIM   512
#define HW      784
#define B_DIM   32
#define T_POS   4                // 4 consecutive n per wg; 32KB LDS -> 5 blocks/CU
#define NTILES  (HW / T_POS)     // 196
#define NTHREADS 128
#define NBLK    (B_DIM * NTILES) // 6272 = 8 * 784 (exact XCD chunking)
#define RPAD    5                // odd-ish pad, 5 coprime 32 -> conflict-free

typedef float v2f __attribute__((ext_vector_type(2)));

// complex multiply via packed fp32: (a.x*b.x - a.y*b.y, a.x*b.y + a.y*b.x)
__device__ __forceinline__ v2f cmul(v2f a, v2f b) {
    v2f bs = __builtin_shufflevector(b, b, 1, 0);   // (b.y, b.x)
    v2f an = {-a.y, a.y};
    return a.x * b + an * bs;
}

static constexpr int REV5[32] = {
    0,16,8,24,4,20,12,28,2,18,10,26,6,22,14,30,
    1,17,9,25,5,21,13,29,3,19,11,27,7,23,15,31};

static constexpr float C32T[16] = {
    1.f, 0.98078528f, 0.92387953f, 0.83146961f,
    0.70710678f, 0.55557023f, 0.38268343f, 0.19509032f,
    0.f, -0.19509032f, -0.38268343f, -0.55557023f,
    -0.70710678f, -0.83146961f, -0.92387953f, -0.98078528f};
static constexpr float S32T[16] = {
    0.f, 0.19509032f, 0.38268343f, 0.55557023f,
    0.70710678f, 0.83146961f, 0.92387953f, 0.98078528f,
    1.f, 0.98078528f, 0.92387953f, 0.83146961f,
    0.70710678f, 0.55557023f, 0.38268343f, 0.19509032f};

// 32-point in-register DIF FFT, FORWARD only (inverse via conjugation).
// Input natural order; output y[i] = X[rev5(i)].
__device__ __forceinline__ void fft32f(v2f y[32]) {
#pragma unroll
    for (int s = 0; s < 5; ++s) {
        const int L = 32 >> s;
        const int h = 16 >> s;
#pragma unroll
        for (int u = 0; u < 16; ++u) {
            const int blk = u >> (4 - s);
            const int t   = u & (h - 1);
            const int i   = blk * L + t;
            const int m   = t << s;            // twiddle index: W32^m
            v2f a = y[i], b = y[i + h];
            y[i] = a + b;
            v2f d = a - b;
            if (m == 0) {
                y[i + h] = d;
            } else if (m == 8) {
                y[i + h] = (v2f){d.y, -d.x};   // * -i  (forward)
            } else {
                y[i + h] = cmul(d, (v2f){C32T[m], -S32T[m]});
            }
        }
    }
}

// Second half of the four-step (forward sign): y[rev5(k2)] = A[p][k2] on entry.
// Twiddle by W1024^(-p*k2) (4 chains, depth ~12), scatter to swizzled rows,
// same-half-wave transpose read, final fft32. Return: y[rev5(k1)] = X[p+32k1].
__device__ __forceinline__ void four_step_Bf(v2f* zg, int p, v2f y[32]) {
    float sv, cv;
    __sincosf(-6.283185307179586f * (float)p * (1.f / 1024.f), &sv, &cv);
    const v2f stw = {cv, sv};                    // W1024^(-p)
    v2f t2  = cmul(stw, stw);
    v2f t4  = cmul(t2, t2);
    v2f s8  = cmul(t4, t4);                      // stw^8
    v2f s16 = cmul(s8, s8);                      // stw^16
    v2f s24 = cmul(s16, s8);                     // stw^24
    v2f wq0 = {1.f, 0.f}, wq1 = s8, wq2 = s16, wq3 = s24;
#pragma unroll
    for (int m = 0; m < 8; ++m) {
        {   const int k2 = m;                     // chain 0
            v2f val = y[REV5[k2]];
            if (k2 > 0) val = cmul(val, wq0);
            zg[k2 * 32 + ((p + k2) & 31)] = val; }
        {   const int k2 = 8 + m;                 // chain 1
            zg[k2 * 32 + ((p + k2) & 31)] = cmul(y[REV5[k2]], wq1); }
        {   const int k2 = 16 + m;                // chain 2
            zg[k2 * 32 + ((p + k2) & 31)] = cmul(y[REV5[k2]], wq2); }
        {   const int k2 = 24 + m;                // chain 3
            zg[k2 * 32 + ((p + k2) & 31)] = cmul(y[REV5[k2]], wq3); }
        if (m < 7) {
            wq0 = cmul(wq0, stw); wq1 = cmul(wq1, stw);
            wq2 = cmul(wq2, stw); wq3 = cmul(wq3, stw);
        }
    }
    __builtin_amdgcn_wave_barrier();
#pragma unroll
    for (int n1 = 0; n1 < 32; ++n1)
        y[n1] = zg[p * 32 + ((n1 + p) & 31)];
    __builtin_amdgcn_wave_barrier();
    fft32f(y);
}

// One block per output row o; lanes sweep c coalesced. Each column c has
// exactly one nonzero across o, so the winning thread writes without races.
__global__ void extract_sketch(const float* __restrict__ sk1,
                               const float* __restrict__ sk2,
                               int* __restrict__ h, float* __restrict__ s) {
    const int o = blockIdx.x;                 // 0..1023
    for (int c = threadIdx.x; c < C_DIM; c += blockDim.x) {
        float v1 = sk1[o * C_DIM + c];
        if (v1 != 0.f) { h[c] = o; s[c] = v1; }
        float v2 = sk2[o * C_DIM + c];
        if (v2 != 0.f) { h[C_DIM + c] = o; s[C_DIM + c] = v2; }
    }
}

__global__ __launch_bounds__(NTHREADS, 2)
void cbp_main(const float* __restrict__ x1, const float* __restrict__ x2,
              const int* __restrict__ h1, const int* __restrict__ h2,
              const float* __restrict__ s1, const float* __restrict__ s2,
              float* __restrict__ out) {
    // 32 KB: Z = [4][1024] complex for scatter+FFT; after the FFTs die the
    // same space is reused as R = [1024][5] floats for the output transpose.
    __shared__ float4 LBUF[2048];
    float* Zs = reinterpret_cast<float*>(LBUF);    // scalar view (atomics)
    float* R  = reinterpret_cast<float*>(LBUF);    // transpose overlay

    const int tid = threadIdx.x;
    // chunked XCD swizzle (8 XCDs, 6272 = 8*784): consecutive work items
    // (same b, adjacent tiles) land on the SAME XCD so the 16B x-reads /
    // 16B out-writes that share a 64B line hit the same L2.
    const int wid  = blockIdx.x;
    const int work = (wid & 7) * (NBLK >> 3) + (wid >> 3);
    const int b    = work / NTILES;
    const int tile = work % NTILES;
    const int n0   = tile * T_POS;

    // ---- prefetch: 4 channel rows per thread, 16 B each ----
    const int xoff = b * (C_DIM * HW) + n0;
    float4 xa[4], xb[4];
    int    qa[4], qb[4];
    float  wa[4], wb[4];
#pragma unroll
    for (int r = 0; r < 4; ++r) {
        const int c = tid + NTHREADS * r;
        xa[r] = *(const float4*)(x1 + xoff + c * HW);
        xb[r] = *(const float4*)(x2 + xoff + c * HW);
        qa[r] = h1[c];  qb[r] = h2[c];
        wa[r] = s1[c];  wb[r] = s2[c];
    }

    // ---- zero LDS (hides the global-load latency) ----
#pragma unroll
    for (int i = 0; i < 2048 / NTHREADS; ++i)
        LBUF[tid + NTHREADS * i] = make_float4(0.f, 0.f, 0.f, 0.f);
    __syncthreads();

    // ---- scatter: Z[pos][h1[c]].x += s1*x1, Z[pos][h2[c]].y += s2*x2 ----
    // workgroup-scoped relaxed fp32 adds -> ds_add_f32 (no CAS loop).
#pragma unroll
    for (int r = 0; r < 4; ++r) {
        float va[4] = {xa[r].x, xa[r].y, xa[r].z, xa[r].w};
#pragma unroll
        for (int j = 0; j < 4; ++j)
            __hip_atomic_fetch_add(&Zs[(j * O_DIM + qa[r]) * 2 + 0],
                                   wa[r] * va[j],
                                   __ATOMIC_RELAXED, __HIP_MEMORY_SCOPE_WORKGROUP);
        float vb[4] = {xb[r].x, xb[r].y, xb[r].z, xb[r].w};
#pragma unroll
        for (int j = 0; j < 4; ++j)
            __hip_atomic_fetch_add(&Zs[(j * O_DIM + qb[r]) * 2 + 1],
                                   wb[r] * vb[j],
                                   __ATOMIC_RELAXED, __HIP_MEMORY_SCOPE_WORKGROUP);
    }
    __syncthreads();

    const int g    = tid >> 5;       // position group 0..3 (half-wave)
    const int p    = tid & 31;
    const int lane = tid & 63;
    v2f* zg = reinterpret_cast<v2f*>(LBUF) + g * O_DIM;
    const int paddr = (((lane & 32) | ((32 - p) & 31))) << 2;

    v2f y[32];

    // Two iterations of the SAME forward-FFT code path (code emitted once):
    //   iter 0: forward FFT of z = p1 + i*p2 from LDS
    //   iter 1: inverse FFT of the Hermitian product via the conjugation
    //           identity IFFT(G) = conj(FFT(conj(G))); conj folded into the
    //           product signs, final conj free (only .x stored).
#pragma unroll 1
    for (int iter = 0; iter < 2; ++iter) {
        if (iter == 0) {
#pragma unroll
            for (int n2 = 0; n2 < 32; ++n2)
                y[n2] = zg[p + 32 * n2];
            __builtin_amdgcn_wave_barrier();
        } else {
            // ---- Hermitian unpack + pointwise product, in registers ----
            // G[k], k = p+32*n2, needs zb = X[1024-k] from lane (32-p)&31,
            // reg REV5[31-n2] (p>=1): fixed half-wave pairing -> bpermute.
            // Lane 0 self-patches from reg REV5[(32-n2)&31].
            v2f t[32];
#pragma unroll
            for (int n2 = 0; n2 < 32; ++n2) {
                v2f za = y[REV5[n2]];
                v2f yb = y[REV5[31 - n2]];
                v2f zb;
                zb.x = __uint_as_float((unsigned)__builtin_amdgcn_ds_bpermute(
                           paddr, (int)__float_as_uint(yb.x)));
                zb.y = __uint_as_float((unsigned)__builtin_amdgcn_ds_bpermute(
                           paddr, (int)__float_as_uint(yb.y)));
                v2f self = y[REV5[(32 - n2) & 31]];
                zb.x = (p == 0) ? self.x : zb.x;
                zb.y = (p == 0) ? self.y : zb.y;
                v2f F1c = { za.x + zb.x, zb.y - za.y };   // conj(2*F1)
                v2f F2c = { za.y + zb.y, za.x - zb.x };   // conj(2*F2)
                t[n2] = cmul(F1c, F2c);                   // conj(4*G[p+32n2])
            }
#pragma unroll
            for (int i = 0; i < 32; ++i) y[i] = t[i];
        }
        fft32f(y);
        four_step_Bf(zg, p, y);
    }
    __syncthreads();              // all groups done with Z before R overlay

    // ---- stage transpose: R[o][g] = conv[pos g][bucket o] ----
#pragma unroll
    for (int k1 = 0; k1 < 32; ++k1)
        R[(p + 32 * k1) * RPAD + g] = y[REV5[k1]].x * (0.25f / 1024.f);
    __syncthreads();

    // ---- store: 16 B (4 consecutive n) per o ----
    const int obase = b * (O_DIM * HW) + n0;
#pragma unroll
    for (int r = 0; r < O_DIM / NTHREADS; ++r) {
        const int o = tid + NTHREADS * r;
        const float* rp = &R[o * RPAD];
        float4 v0 = make_float4(rp[0], rp[1], rp[2], rp[3]);
        *(float4*)(out + obase + o * HW) = v0;
    }
}

extern "C" void kernel_launch(void* const* d_in, const int* in_sizes, int n_in,
                              void* d_out, int out_size, void* d_ws, size_t ws_size,
                              hipStream_t stream) {
    const float* x1  = (const float*)d_in[0];
    const float* x2  = (const float*)d_in[1];
    const float* sk1 = (const float*)d_in[2];
    const float* sk2 = (const float*)d_in[3];
    float* out = (float*)d_out;

    int*   h = (int*)d_ws;                         // [0..511]=h1, [512..1023]=h2
    float* s = (float*)((char*)d_ws + 4096);       // [0..511]=s1, [512..1023]=s2

    hipLaunchKernelGGL(extract_sketch, dim3(O_DIM), dim3(256), 0, stream,
                       sk1, sk2, h, s);
    hipLaunchKernelGGL(cbp_main, dim3(NBLK), dim3(NTHREADS), 0, stream,
                       x1, x2, h, h + C_DIM, s, s + C_DIM, out);
}

// Round 6
// 348.394 us; speedup vs baseline: 1.0322x; 1.0151x over previous
//
#include <hip/hip_runtime.h>

#define O_DIM   1024
#define C_DIM   512
#define HW      784
#define B_DIM   32
#define T_POS   4                // 4 consecutive n per wg; 32KB LDS
#define NTILES  (HW / T_POS)     // 196
#define NTHREADS 256             // 4 waves; ONE WAVE PER FFT ROW (64-lane rows)
#define NBLK    (B_DIM * NTILES) // 6272 = 8 * 784 (exact XCD chunking)
#define RPAD    5                // 5 coprime 32 -> conflict-free transpose

typedef float v2f __attribute__((ext_vector_type(2)));

// complex multiply via packed fp32
__device__ __forceinline__ v2f cmul(v2f a, v2f b) {
    v2f bs = __builtin_shufflevector(b, b, 1, 0);   // (b.y, b.x)
    v2f an = {-a.y, a.y};
    return a.x * b + an * bs;
}

__device__ __forceinline__ v2f bperm(int addr, v2f v) {
    v2f r;
    r.x = __uint_as_float((unsigned)__builtin_amdgcn_ds_bpermute(
              addr, (int)__float_as_uint(v.x)));
    r.y = __uint_as_float((unsigned)__builtin_amdgcn_ds_bpermute(
              addr, (int)__float_as_uint(v.y)));
    return r;
}

static constexpr int REV4[16] = {0,8,4,12,2,10,6,14,1,9,5,13,3,11,7,15};
// c==0,h==0 product self-patch reg: REV4[(16-REV4[j])&15]
static constexpr int J0A[16]  = {0,1,3,2,7,6,5,4,15,14,13,12,11,10,9,8};

static constexpr float C32T[16] = {
    1.f, 0.98078528f, 0.92387953f, 0.83146961f,
    0.70710678f, 0.55557023f, 0.38268343f, 0.19509032f,
    0.f, -0.19509032f, -0.38268343f, -0.55557023f,
    -0.70710678f, -0.83146961f, -0.92387953f, -0.98078528f};
static constexpr float S32T[16] = {
    0.f, 0.19509032f, 0.38268343f, 0.55557023f,
    0.70710678f, 0.83146961f, 0.92387953f, 0.98078528f,
    1.f, 0.98078528f, 0.92387953f, 0.83146961f,
    0.70710678f, 0.55557023f, 0.38268343f, 0.19509032f};

// Forward 32-point DIF FFT split across the two 32-lane halves of a wave.
// Lane (c,h) enters with y[j] = x[16h+j]; exit: slot j5=(h<<4)|j holds
// X32[rev5(j5)] (i.e. y[j] = X32[2*rev4(j)+h]).
__device__ __forceinline__ void fft32x(v2f y[16], int h, int xaddr) {
#pragma unroll
    for (int j = 0; j < 16; ++j) {
        v2f own = y[j];
        v2f oth = bperm(xaddr, own);
        v2f sum = own + oth;            // lo half: a + b
        v2f f   = own - oth;            // hi half: b - a
        v2f dd;                         // hi needs (a-b)*W32^j = f * (-W32^j)
        if (j == 0)      dd = -f;
        else if (j == 8) dd = (v2f){-f.y, f.x};
        else             dd = cmul(f, (v2f){-C32T[j], S32T[j]});
        y[j].x = h ? dd.x : sum.x;
        y[j].y = h ? dd.y : sum.y;
    }
    // local 16-point forward DIF (= stages 1..4 of the 32-pt FFT)
#pragma unroll
    for (int s = 0; s < 4; ++s) {
        const int hh = 8 >> s;
        const int L  = 16 >> s;
#pragma unroll
        for (int u = 0; u < 8; ++u) {
            const int blk = u >> (3 - s);
            const int t   = u & (hh - 1);
            const int i   = blk * L + t;
            const int m   = (t << s) * 2;      // twiddle W32^m == W16^(t<<s)
            v2f a = y[i], b = y[i + hh];
            y[i] = a + b;
            v2f d = a - b;
            if (m == 0)      y[i + hh] = d;
            else if (m == 8) y[i + hh] = (v2f){d.y, -d.x};
            else             y[i + hh] = cmul(d, (v2f){C32T[m], -S32T[m]});
        }
    }
}

// Forward 32-point DIT FFT: consumes the BIT-REVERSED slot layout the DIF
// produces (slot j5 holds x[rev5(j5)]) and outputs NATURAL order
// (y[j] = X32[16h+j]). 4 lane-local DIT stages (slot bits 0..3) + one
// cross-half stage (slot bit 4 = h): X[k]=E[k]+W32^k*O[k], X[k+16]=E[k]-...
__device__ __forceinline__ void fft32x_dit(v2f y[16], int h, int xaddr) {
#pragma unroll
    for (int s = 0; s < 4; ++s) {
        const int half = 1 << s;
        const int lowmask = half - 1;
#pragma unroll
        for (int u = 0; u < 8; ++u) {
            const int i = ((u & ~lowmask) << 1) | (u & lowmask);
            const int m = (i & lowmask) * (16 >> s);   // W32^m
            v2f a = y[i], b = y[i + half];
            v2f t;
            if (m == 0)      t = b;
            else if (m == 8) t = (v2f){b.y, -b.x};
            else             t = cmul(b, (v2f){C32T[m], -S32T[m]});
            y[i]        = a + t;
            y[i + half] = a - t;
        }
    }
    // cross-half final stage: lo lane own=E[j], oth=O[j] -> E + W^j*O
    //                         hi lane own=O[j], oth=E[j] -> E - W^j*O
#pragma unroll
    for (int j = 0; j < 16; ++j) {
        v2f own = y[j];
        v2f oth = bperm(xaddr, own);
        v2f aa, bb;
        aa.x = h ? oth.x : own.x;  aa.y = h ? oth.y : own.y;   // E[j]
        bb.x = h ? own.x : oth.x;  bb.y = h ? own.y : oth.y;   // O[j]
        v2f t;
        if (j == 0)      t = bb;
        else if (j == 8) t = (v2f){bb.y, -bb.x};
        else             t = cmul(bb, (v2f){C32T[j], -S32T[j]});
        y[j].x = h ? aa.x - t.x : aa.x + t.x;
        y[j].y = h ? aa.y - t.y : aa.y + t.y;
    }
}

// One block per output row o; lanes sweep c coalesced. Each column c has
// exactly one nonzero across o, so the winning thread writes without races.
__global__ void extract_sketch(const float* __restrict__ sk1,
                               const float* __restrict__ sk2,
                               int* __restrict__ h, float* __restrict__ s) {
    const int o = blockIdx.x;                 // 0..1023
    for (int c = threadIdx.x; c < C_DIM; c += blockDim.x) {
        float v1 = sk1[o * C_DIM + c];
        if (v1 != 0.f) { h[c] = o; s[c] = v1; }
        float v2 = sk2[o * C_DIM + c];
        if (v2 != 0.f) { h[C_DIM + c] = o; s[C_DIM + c] = v2; }
    }
}

__global__ __launch_bounds__(NTHREADS, 4)
void cbp_main(const float* __restrict__ x1, const float* __restrict__ x2,
              const int* __restrict__ h1, const int* __restrict__ h2,
              const float* __restrict__ s1, const float* __restrict__ s2,
              float* __restrict__ out) {
    // 32 KB: Z = [4][1024] complex for scatter+FFT; after the FFTs die the
    // same space is reused as R = [1024][5] floats for the output transpose.
    __shared__ float4 LBUF[2048];
    float* Zs = reinterpret_cast<float*>(LBUF);    // scalar view (atomics)
    float* R  = reinterpret_cast<float*>(LBUF);    // transpose overlay

    const int tid = threadIdx.x;
    // chunked XCD swizzle (8 XCDs, 6272 = 8*784): adjacent work items land
    // on the same XCD so 16B accesses sharing a 64B line hit the same L2.
    const int wid  = blockIdx.x;
    const int work = (wid & 7) * (NBLK >> 3) + (wid >> 3);
    const int b    = work / NTILES;
    const int tile = work % NTILES;
    const int n0   = tile * T_POS;

    // ---- prefetch: 2 channel rows per thread per input, 16 B each ----
    const int c0 = tid;
    const int c1 = tid + NTHREADS;
    const int xoff = b * (C_DIM * HW) + n0;
    float4 xa0 = *(const float4*)(x1 + xoff + c0 * HW);
    float4 xa1 = *(const float4*)(x1 + xoff + c1 * HW);
    float4 xb0 = *(const float4*)(x2 + xoff + c0 * HW);
    float4 xb1 = *(const float4*)(x2 + xoff + c1 * HW);
    const int   q10 = h1[c0], q11 = h1[c1], q20 = h2[c0], q21 = h2[c1];
    const float w10 = s1[c0], w11 = s1[c1], w20 = s2[c0], w21 = s2[c1];

    // ---- zero LDS (hides the global-load latency) ----
#pragma unroll
    for (int i = 0; i < 2048 / NTHREADS; ++i)
        LBUF[tid + NTHREADS * i] = make_float4(0.f, 0.f, 0.f, 0.f);
    __syncthreads();

    // ---- scatter: Z[pos][h1[c]].x += s1*x1, Z[pos][h2[c]].y += s2*x2 ----
    // workgroup-scoped relaxed fp32 adds -> ds pipe atomic, no CAS loop
    {
        float va[4] = {xa0.x, xa0.y, xa0.z, xa0.w};
#pragma unroll
        for (int j = 0; j < 4; ++j)
            __hip_atomic_fetch_add(&Zs[(j * O_DIM + q10) * 2 + 0], w10 * va[j],
                                   __ATOMIC_RELAXED, __HIP_MEMORY_SCOPE_WORKGROUP);
        float vb[4] = {xa1.x, xa1.y, xa1.z, xa1.w};
#pragma unroll
        for (int j = 0; j < 4; ++j)
            __hip_atomic_fetch_add(&Zs[(j * O_DIM + q11) * 2 + 0], w11 * vb[j],
                                   __ATOMIC_RELAXED, __HIP_MEMORY_SCOPE_WORKGROUP);
        float vc[4] = {xb0.x, xb0.y, xb0.z, xb0.w};
#pragma unroll
        for (int j = 0; j < 4; ++j)
            __hip_atomic_fetch_add(&Zs[(j * O_DIM + q20) * 2 + 1], w20 * vc[j],
                                   __ATOMIC_RELAXED, __HIP_MEMORY_SCOPE_WORKGROUP);
        float vd[4] = {xb1.x, xb1.y, xb1.z, xb1.w};
#pragma unroll
        for (int j = 0; j < 4; ++j)
            __hip_atomic_fetch_add(&Zs[(j * O_DIM + q21) * 2 + 1], w21 * vd[j],
                                   __ATOMIC_RELAXED, __HIP_MEMORY_SCOPE_WORKGROUP);
    }
    __syncthreads();

    const int wv   = tid >> 6;       // wave id = position row 0..3
    const int lane = tid & 63;
    const int c    = lane & 31;      // column within the 32x32 four-step
    const int h    = lane >> 5;      // half: owns n-range [16h, 16h+16)
    v2f* zg = reinterpret_cast<v2f*>(LBUF) + wv * O_DIM;
    const int xaddr = (lane ^ 32) << 2;                          // cross-half
    const int paddr = ((((32 - c) & 31) | ((1 - h) << 5)) << 2); // product partner

    float sv, cv;
    __sincosf(-6.283185307179586f * (float)c * (1.f / 1024.f), &sv, &cv);
    const v2f cs = {cv, sv};         // W1024^c (forward-sign twiddle base)

    v2f y[16];

    // ================= PASS 1: forward FFT of z = p1 + i*p2 =============
#pragma unroll
    for (int j = 0; j < 16; ++j)                 // column c, n2 = 16h + j
        y[j] = zg[c + 32 * (16 * h + j)];
    __builtin_amdgcn_wave_barrier();
    fft32x(y, h, xaddr);                         // y[j] = A_c[2*rev4(j)+h]

    // twiddle W1024^(c*k2), k2 = 2m+h (bit-reversed A layout), scatter
    {
        v2f step  = cmul(cs, cs);
        v2f st2   = cmul(step, step);
        v2f st4   = cmul(st2, st2);
        v2f st8   = cmul(st4, st4);
        v2f st12  = cmul(st8, st4);
        v2f base;
        base.x = h ? cs.x : 1.f;
        base.y = h ? cs.y : 0.f;
        v2f w0 = base, w1 = cmul(base, st4), w2 = cmul(base, st8),
            w3 = cmul(base, st12);
#pragma unroll
        for (int mm = 0; mm < 4; ++mm) {
            {   const int m = mm;          const int k2 = 2 * m + h;
                zg[k2 * 32 + ((c + k2) & 31)] = cmul(y[REV4[m]], w0); }
            {   const int m = 4 + mm;      const int k2 = 2 * m + h;
                zg[k2 * 32 + ((c + k2) & 31)] = cmul(y[REV4[m]], w1); }
            {   const int m = 8 + mm;      const int k2 = 2 * m + h;
                zg[k2 * 32 + ((c + k2) & 31)] = cmul(y[REV4[m]], w2); }
            {   const int m = 12 + mm;     const int k2 = 2 * m + h;
                zg[k2 * 32 + ((c + k2) & 31)] = cmul(y[REV4[m]], w3); }
            if (mm < 3) {
                w0 = cmul(w0, step); w1 = cmul(w1, step);
                w2 = cmul(w2, step); w3 = cmul(w3, step);
            }
        }
    }
    __builtin_amdgcn_wave_barrier();
#pragma unroll
    for (int j = 0; j < 16; ++j)                 // row c, n1 = 16h+j, swizzled
        y[j] = zg[c * 32 + ((16 * h + j + c) & 31)];
    __builtin_amdgcn_wave_barrier();
    fft32x(y, h, xaddr);
    // slot j5=(h<<4)|j holds X[c + 32*rev5(j5)]  (spectral, bit-reversed)

    // ===== Hermitian unpack + pointwise product (spectral slot layout) ====
    // Partner of slot j5 is slot 31-j5 of column 32-c: lane (32-c,1-h),
    // reg 15-j. c==0 self-patches: h==1 -> reg 15-j; h==0 -> reg J0A[j].
    // k=0 / k=512 (za==zb) fall out of the general formula.
    {
        v2f t[16];
#pragma unroll
        for (int j = 0; j < 16; ++j) {
            v2f za   = y[j];
            v2f push = y[15 - j];
            v2f zb   = bperm(paddr, push);
            v2f selfA = y[J0A[j]];
            v2f self;
            self.x = h ? push.x : selfA.x;
            self.y = h ? push.y : selfA.y;
            zb.x = (c == 0) ? self.x : zb.x;
            zb.y = (c == 0) ? self.y : zb.y;
            v2f F1c = { za.x + zb.x, zb.y - za.y };   // conj(2*F1)
            v2f F2c = { za.y + zb.y, za.x - zb.x };   // conj(2*F2)
            t[j] = cmul(F1c, F2c);                    // conj(4*G), same slot
        }
#pragma unroll
        for (int j = 0; j < 16; ++j) y[j] = t[j];
    }

    // ====== PASS 2: inverse FFT via conj identity, DIT consumes the ======
    // ====== bit-reversed product layout directly (no reordering)     ======
    fft32x_dit(y, h, xaddr);                     // y[j] = A'_c[16h+j] natural

    // twiddle W1024^(c*k2), k2 = 16h+j (natural layout), scatter
    {
        v2f cs2  = cmul(cs, cs);
        v2f cs4  = cmul(cs2, cs2);
        v2f cs8  = cmul(cs4, cs4);
        v2f cs12 = cmul(cs8, cs4);
        v2f cs16 = cmul(cs8, cs8);
        v2f base;
        base.x = h ? cs16.x : 1.f;
        base.y = h ? cs16.y : 0.f;
        v2f w0 = base, w1 = cmul(base, cs4), w2 = cmul(base, cs8),
            w3 = cmul(base, cs12);
#pragma unroll
        for (int mm = 0; mm < 4; ++mm) {
            {   const int j = mm;          const int k2 = 16 * h + j;
                zg[k2 * 32 + ((c + k2) & 31)] = cmul(y[j], w0); }
            {   const int j = 4 + mm;      const int k2 = 16 * h + j;
                zg[k2 * 32 + ((c + k2) & 31)] = cmul(y[j], w1); }
            {   const int j = 8 + mm;      const int k2 = 16 * h + j;
                zg[k2 * 32 + ((c + k2) & 31)] = cmul(y[j], w2); }
            {   const int j = 12 + mm;     const int k2 = 16 * h + j;
                zg[k2 * 32 + ((c + k2) & 31)] = cmul(y[j], w3); }
            if (mm < 3) {
                w0 = cmul(w0, cs); w1 = cmul(w1, cs);
                w2 = cmul(w2, cs); w3 = cmul(w3, cs);
            }
        }
    }
    __builtin_amdgcn_wave_barrier();
#pragma unroll
    for (int j = 0; j < 16; ++j)                 // row c, n1 = 16h+j, swizzled
        y[j] = zg[c * 32 + ((16 * h + j + c) & 31)];
    __builtin_amdgcn_wave_barrier();
    fft32x(y, h, xaddr);            // y[j] = result[c + 32*(2*rev4(j)+h)]
    __syncthreads();                // all waves done with Z before R overlay

    // ---- stage transpose: R[o][wv] = conv[pos wv][bucket o] ----
#pragma unroll
    for (int j = 0; j < 16; ++j)
        R[(c + 32 * (2 * REV4[j] + h)) * RPAD + wv] = y[j].x * (0.25f / 1024.f);
    __syncthreads();

    // ---- store: 16 B (4 consecutive n) per o ----
    const int obase = b * (O_DIM * HW) + n0;
#pragma unroll
    for (int r = 0; r < O_DIM / NTHREADS; ++r) {
        const int o = tid + NTHREADS * r;
        const float* rp = &R[o * RPAD];
        float4 v0 = make_float4(rp[0], rp[1], rp[2], rp[3]);
        *(float4*)(out + obase + o * HW) = v0;
    }
}

extern "C" void kernel_launch(void* const* d_in, const int* in_sizes, int n_in,
                              void* d_out, int out_size, void* d_ws, size_t ws_size,
                              hipStream_t stream) {
    const float* x1  = (const float*)d_in[0];
    const float* x2  = (const float*)d_in[1];
    const float* sk1 = (const float*)d_in[2];
    const float* sk2 = (const float*)d_in[3];
    float* out = (float*)d_out;

    int*   h = (int*)d_ws;                         // [0..511]=h1, [512..1023]=h2
    float* s = (float*)((char*)d_ws + 4096);       // [0..511]=s1, [512..1023]=s2

    hipLaunchKernelGGL(extract_sketch, dim3(O_DIM), dim3(256), 0, stream,
                       sk1, sk2, h, s);
    hipLaunchKernelGGL(cbp_main, dim3(NBLK), dim3(NTHREADS), 0, stream,
                       x1, x2, h, h + C_DIM, s, s + C_DIM, out);
}